// Round 1
// baseline (734.061 us; speedup 1.0000x reference)
//
#include <hip/hip_runtime.h>

// ---------- helpers ----------
static __device__ __forceinline__ unsigned short f2bf(float f) {
    union { float f; unsigned int u; } c; c.f = f;
    unsigned int u = c.u;
    return (unsigned short)((u + 0x7FFFu + ((u >> 16) & 1u)) >> 16);  // RNE
}
static __device__ __forceinline__ float bf2f(unsigned int hbits) {
    union { unsigned int u; float f; } c; c.u = hbits << 16; return c.f;
}

typedef __bf16 bf16x8 __attribute__((ext_vector_type(8)));
typedef float  f32x4  __attribute__((ext_vector_type(4)));

// ---------- pack W1 [256][128] f32 -> Bt [256][128] bf16 ----------
// Bt[j][k] = (j<128) ? W1[k][j] : W1[128+k][j-128]
// so that UV[n][j] = sum_k x[n][k] * Bt[j][k]  (u for j<128, v for j>=128)
__global__ void k_pack(const float* __restrict__ W1, unsigned short* __restrict__ Bt) {
    int idx = blockIdx.x * blockDim.x + threadIdx.x;   // 32768 total
    int j = idx >> 7, k = idx & 127;
    int r = (j < 128) ? k : (128 + k);
    int c = j & 127;
    Bt[idx] = f2bf(W1[r * 128 + c]);
}

// ---------- GEMM: UV[M][256] = x[M][128] @ Bt^T, bf16 MFMA 16x16x32 ----------
// grid = (ceil(M/64), 4), block = 256 (4 waves). wave w: rows [b*64+w*16, +16),
// cols [blockIdx.y*64, +64). No LDS: Bt (64KB) is L1/L2 hot; x rows reused 4x in L2.
__global__ __launch_bounds__(256) void k_gemm(const float* __restrict__ x,
                                              const unsigned short* __restrict__ Bt,
                                              unsigned short* __restrict__ UV, int M) {
    int wave = threadIdx.x >> 6, lane = threadIdx.x & 63;
    int row0 = blockIdx.x * 64 + wave * 16;
    int col0 = blockIdx.y * 64;
    int lr = lane & 15;              // A row / B col within fragment
    int lk = (lane >> 4) << 3;       // k sub-offset: lane>>4 selects 8-contig k group

    f32x4 acc[4] = {};
    int arow = row0 + lr;
    bool in = (arow < M);
    const float* xr = x + (size_t)arow * 128;

#pragma unroll
    for (int kk = 0; kk < 4; ++kk) {
        int k = kk * 32 + lk;
        union { bf16x8 v; unsigned short u[8]; } ua;
        if (in) {
            float4 f0 = *(const float4*)(xr + k);
            float4 f1 = *(const float4*)(xr + k + 4);
            ua.u[0] = f2bf(f0.x); ua.u[1] = f2bf(f0.y);
            ua.u[2] = f2bf(f0.z); ua.u[3] = f2bf(f0.w);
            ua.u[4] = f2bf(f1.x); ua.u[5] = f2bf(f1.y);
            ua.u[6] = f2bf(f1.z); ua.u[7] = f2bf(f1.w);
        } else {
#pragma unroll
            for (int i = 0; i < 8; ++i) ua.u[i] = 0;
        }
#pragma unroll
        for (int nf = 0; nf < 4; ++nf) {
            int col = col0 + nf * 16 + lr;
            bf16x8 b = *(const bf16x8*)(Bt + col * 128 + k);
            acc[nf] = __builtin_amdgcn_mfma_f32_16x16x32_bf16(ua.v, b, acc[nf], 0, 0, 0);
        }
    }
    // C/D layout (verified m89): col = lane&15, row = (lane>>4)*4 + reg
    int rb = row0 + ((lane >> 4) << 2);
#pragma unroll
    for (int nf = 0; nf < 4; ++nf) {
        int feat = col0 + nf * 16 + lr;
#pragma unroll
        for (int r = 0; r < 4; ++r) {
            int node = rb + r;
            if (node < M) UV[(size_t)node * 256 + feat] = f2bf(acc[nf][r]);
        }
    }
}

// ---------- edge kernel: w_e = sigmoid(relu(u[s]+v[t]+b1) . W2 + b2);
//            atomic scatter: out[t] += w_e * x[s] ----------
__global__ __launch_bounds__(256) void k_edge(const int* __restrict__ ei,
                                              const unsigned short* __restrict__ UV,
                                              const float* __restrict__ x,
                                              const float* __restrict__ b1,
                                              const float* __restrict__ W2,
                                              const float* __restrict__ b2,
                                              float* __restrict__ out, int E) {
    int lane = threadIdx.x & 63;
    int wid  = (blockIdx.x * blockDim.x + threadIdx.x) >> 6;
    int nw   = (gridDim.x * blockDim.x) >> 6;

    // per-lane constants: features 2*lane, 2*lane+1
    float b1_0 = b1[2 * lane], b1_1 = b1[2 * lane + 1];
    float w2_0 = W2[2 * lane], w2_1 = W2[2 * lane + 1];
    float b2s  = b2[0];

    for (int e = wid; e < E; e += nw) {
        int s = ei[e];
        int t = ei[E + e];
        unsigned int uu = *(const unsigned int*)(UV + (size_t)s * 256 + 2 * lane);
        unsigned int vv = *(const unsigned int*)(UV + (size_t)t * 256 + 128 + 2 * lane);
        float h0 = bf2f(uu & 0xFFFFu) + bf2f(vv & 0xFFFFu) + b1_0;
        float h1 = bf2f(uu >> 16)     + bf2f(vv >> 16)     + b1_1;
        h0 = fmaxf(h0, 0.0f);
        h1 = fmaxf(h1, 0.0f);
        float p = h0 * w2_0 + h1 * w2_1;
#pragma unroll
        for (int off = 32; off; off >>= 1) p += __shfl_xor(p, off);
        float w = 1.0f / (1.0f + __expf(-(p + b2s)));

        float2 xs = *(const float2*)(x + (size_t)s * 128 + 2 * lane);
        atomicAdd(out + (size_t)t * 128 + 2 * lane,     w * xs.x);
        atomicAdd(out + (size_t)t * 128 + 2 * lane + 1, w * xs.y);
    }
}

// ---------- LayerNorm in place: out = LN(x + out) * gamma + beta ----------
__global__ __launch_bounds__(256) void k_ln(const float* __restrict__ x,
                                            const float* __restrict__ gamma,
                                            const float* __restrict__ beta,
                                            float* __restrict__ out, int N) {
    int row = blockIdx.x * 4 + (threadIdx.x >> 6);
    if (row >= N) return;
    int lane = threadIdx.x & 63;
    const float2* xr = (const float2*)(x + (size_t)row * 128);
    float2* orow = (float2*)(out + (size_t)row * 128);
    float2 a = orow[lane];
    float2 xx = xr[lane];
    float a0 = a.x + xx.x, a1 = a.y + xx.y;
    float s = a0 + a1;
#pragma unroll
    for (int off = 32; off; off >>= 1) s += __shfl_xor(s, off);
    float mu = s * (1.0f / 128.0f);
    float d0 = a0 - mu, d1 = a1 - mu;
    float q = d0 * d0 + d1 * d1;
#pragma unroll
    for (int off = 32; off; off >>= 1) q += __shfl_xor(q, off);
    float rstd = rsqrtf(q * (1.0f / 128.0f) + 1e-5f);
    float g0 = gamma[2 * lane], g1 = gamma[2 * lane + 1];
    float e0 = beta[2 * lane],  e1 = beta[2 * lane + 1];
    float2 o;
    o.x = d0 * rstd * g0 + e0;
    o.y = d1 * rstd * g1 + e1;
    orow[lane] = o;
}

extern "C" void kernel_launch(void* const* d_in, const int* in_sizes, int n_in,
                              void* d_out, int out_size, void* d_ws, size_t ws_size,
                              hipStream_t stream) {
    const float* x     = (const float*)d_in[0];
    const int*   ei    = (const int*)d_in[1];
    const float* W1    = (const float*)d_in[2];
    const float* b1    = (const float*)d_in[3];
    const float* W2    = (const float*)d_in[4];
    const float* b2    = (const float*)d_in[5];
    const float* gamma = (const float*)d_in[6];
    const float* beta  = (const float*)d_in[7];
    float* out = (float*)d_out;

    const int N = in_sizes[0] / 128;   // 50000
    const int E = in_sizes[1] / 2;     // 800000

    // workspace: Bt (bf16, 256*128 = 64KB) | UV (bf16, N*256 = 25.6MB)
    unsigned short* Bt = (unsigned short*)d_ws;
    unsigned short* UV = Bt + 256 * 128;

    hipMemsetAsync(d_out, 0, (size_t)N * 128 * sizeof(float), stream);

    k_pack<<<128, 256, 0, stream>>>(W1, Bt);

    dim3 ggrid((N + 63) / 64, 4);
    k_gemm<<<ggrid, 256, 0, stream>>>(x, Bt, UV, N);

    k_edge<<<2048, 256, 0, stream>>>(ei, UV, x, b1, W2, b2, out, E);

    k_ln<<<(N + 3) / 4, 256, 0, stream>>>(x, gamma, beta, out, N);
}

// Round 2
// 292.530 us; speedup vs baseline: 2.5094x; 2.5094x over previous
//
#include <hip/hip_runtime.h>

// ---------- helpers ----------
static __device__ __forceinline__ unsigned short f2bf(float f) {
    union { float f; unsigned int u; } c; c.f = f;
    unsigned int u = c.u;
    return (unsigned short)((u + 0x7FFFu + ((u >> 16) & 1u)) >> 16);  // RNE
}
static __device__ __forceinline__ float bf2f(unsigned int hbits) {
    union { unsigned int u; float f; } c; c.u = hbits << 16; return c.f;
}

typedef __bf16 bf16x8 __attribute__((ext_vector_type(8)));
typedef float  f32x4  __attribute__((ext_vector_type(4)));

// ---------- pack W1 [256][128] f32 -> Bt [256][128] bf16 ----------
__global__ void k_pack(const float* __restrict__ W1, unsigned short* __restrict__ Bt) {
    int idx = blockIdx.x * blockDim.x + threadIdx.x;   // 32768 total
    int j = idx >> 7, k = idx & 127;
    int r = (j < 128) ? k : (128 + k);
    int c = j & 127;
    Bt[idx] = f2bf(W1[r * 128 + c]);
}

// ---------- GEMM: UV[M][256] = x[M][128] @ Bt^T, bf16 MFMA 16x16x32 ----------
__global__ __launch_bounds__(256) void k_gemm(const float* __restrict__ x,
                                              const unsigned short* __restrict__ Bt,
                                              unsigned short* __restrict__ UV, int M) {
    int wave = threadIdx.x >> 6, lane = threadIdx.x & 63;
    int row0 = blockIdx.x * 64 + wave * 16;
    int col0 = blockIdx.y * 64;
    int lr = lane & 15;
    int lk = (lane >> 4) << 3;

    f32x4 acc[4] = {};
    int arow = row0 + lr;
    bool in = (arow < M);
    const float* xr = x + (size_t)arow * 128;

#pragma unroll
    for (int kk = 0; kk < 4; ++kk) {
        int k = kk * 32 + lk;
        union { bf16x8 v; unsigned short u[8]; } ua;
        if (in) {
            float4 f0 = *(const float4*)(xr + k);
            float4 f1 = *(const float4*)(xr + k + 4);
            ua.u[0] = f2bf(f0.x); ua.u[1] = f2bf(f0.y);
            ua.u[2] = f2bf(f0.z); ua.u[3] = f2bf(f0.w);
            ua.u[4] = f2bf(f1.x); ua.u[5] = f2bf(f1.y);
            ua.u[6] = f2bf(f1.z); ua.u[7] = f2bf(f1.w);
        } else {
#pragma unroll
            for (int i = 0; i < 8; ++i) ua.u[i] = 0;
        }
#pragma unroll
        for (int nf = 0; nf < 4; ++nf) {
            int col = col0 + nf * 16 + lr;
            bf16x8 b = *(const bf16x8*)(Bt + col * 128 + k);
            acc[nf] = __builtin_amdgcn_mfma_f32_16x16x32_bf16(ua.v, b, acc[nf], 0, 0, 0);
        }
    }
    int rb = row0 + ((lane >> 4) << 2);
#pragma unroll
    for (int nf = 0; nf < 4; ++nf) {
        int feat = col0 + nf * 16 + lr;
#pragma unroll
        for (int r = 0; r < 4; ++r) {
            int node = rb + r;
            if (node < M) UV[(size_t)node * 256 + feat] = f2bf(acc[nf][r]);
        }
    }
}

// ---------- histogram of targets ----------
__global__ void k_hist(const int* __restrict__ ei, int* __restrict__ deg, int E) {
    int e = blockIdx.x * blockDim.x + threadIdx.x;
    if (e < E) atomicAdd(deg + ei[E + e], 1);
}

// ---------- scan stage 1: in-place per-block exclusive scan + block sums ----------
__global__ void k_scan1(int* __restrict__ a, int* __restrict__ bsum, int N) {
    __shared__ int s0[256], s1[256];
    int tid = threadIdx.x;
    int n = blockIdx.x * 256 + tid;
    int v = (n < N) ? a[n] : 0;
    s0[tid] = v;
    __syncthreads();
    int* cur = s0; int* nxt = s1;
#pragma unroll
    for (int off = 1; off < 256; off <<= 1) {
        int val = cur[tid];
        if (tid >= off) val += cur[tid - off];
        nxt[tid] = val;
        __syncthreads();
        int* t = cur; cur = nxt; nxt = t;
    }
    if (n < N) a[n] = cur[tid] - v;               // exclusive within block
    if (tid == 255) bsum[blockIdx.x] = cur[255];  // block total
}

// ---------- scan stage 2: exclusive scan of block sums (nb <= 256), one block ----------
__global__ void k_scan2(int* __restrict__ bsum, int nb) {
    __shared__ int s0[256], s1[256];
    int tid = threadIdx.x;
    int v = (tid < nb) ? bsum[tid] : 0;
    s0[tid] = v;
    __syncthreads();
    int* cur = s0; int* nxt = s1;
#pragma unroll
    for (int off = 1; off < 256; off <<= 1) {
        int val = cur[tid];
        if (tid >= off) val += cur[tid - off];
        nxt[tid] = val;
        __syncthreads();
        int* t = cur; cur = nxt; nxt = t;
    }
    if (tid < nb) bsum[tid] = cur[tid] - v;       // exclusive
}

// ---------- scan stage 3: add block offsets; init cursor; rowstart[N]=E ----------
__global__ void k_scan3(int* __restrict__ rowstart, const int* __restrict__ bsum,
                        int* __restrict__ cursor, int N, int E) {
    int n = blockIdx.x * 256 + threadIdx.x;
    if (n < N) {
        int r = rowstart[n] + bsum[n >> 8];
        rowstart[n] = r;
        cursor[n] = r;
    }
    if (n == 0) rowstart[N] = E;
}

// ---------- edge weights + bucket scatter: esrc[p]=s, ew[p]=w ----------
__global__ __launch_bounds__(256) void k_wsc(const int* __restrict__ ei,
                                             const unsigned short* __restrict__ UV,
                                             const float* __restrict__ b1,
                                             const float* __restrict__ W2,
                                             const float* __restrict__ b2,
                                             int* __restrict__ cursor,
                                             int* __restrict__ esrc,
                                             float* __restrict__ ew, int E) {
    int lane = threadIdx.x & 63;
    int wid  = (blockIdx.x * blockDim.x + threadIdx.x) >> 6;
    int nw   = (gridDim.x * blockDim.x) >> 6;

    float b1_0 = b1[2 * lane], b1_1 = b1[2 * lane + 1];
    float w2_0 = W2[2 * lane], w2_1 = W2[2 * lane + 1];
    float b2s  = b2[0];

    for (int e = wid; e < E; e += nw) {
        int s = ei[e];
        int t = ei[E + e];
        unsigned int uu = *(const unsigned int*)(UV + (size_t)s * 256 + 2 * lane);
        unsigned int vv = *(const unsigned int*)(UV + (size_t)t * 256 + 128 + 2 * lane);
        float h0 = bf2f(uu & 0xFFFFu) + bf2f(vv & 0xFFFFu) + b1_0;
        float h1 = bf2f(uu >> 16)     + bf2f(vv >> 16)     + b1_1;
        float p = fmaxf(h0, 0.0f) * w2_0 + fmaxf(h1, 0.0f) * w2_1;
#pragma unroll
        for (int off = 32; off; off >>= 1) p += __shfl_xor(p, off);
        if (lane == 0) {
            float w = 1.0f / (1.0f + __expf(-(p + b2s)));
            int pos = atomicAdd(cursor + t, 1);
            esrc[pos] = s;
            ew[pos]   = w;
        }
    }
}

// ---------- gather-aggregate + fused LayerNorm: one wave per node ----------
__global__ __launch_bounds__(256) void k_aggln(const float* __restrict__ x,
                                               const int* __restrict__ rowstart,
                                               const int* __restrict__ esrc,
                                               const float* __restrict__ ew,
                                               const float* __restrict__ gamma,
                                               const float* __restrict__ beta,
                                               float* __restrict__ out, int N) {
    int row = blockIdx.x * 4 + (threadIdx.x >> 6);
    if (row >= N) return;
    int lane = threadIdx.x & 63;

    int st = rowstart[row];
    int en = rowstart[row + 1];

    float2 xx = *(const float2*)(x + (size_t)row * 128 + 2 * lane);
    float a0 = xx.x, a1 = xx.y;

    int k = st;
    for (; k + 2 <= en; k += 2) {
        int s0 = esrc[k], s1v = esrc[k + 1];
        float w0 = ew[k], w1 = ew[k + 1];
        float2 f0 = *(const float2*)(x + (size_t)s0  * 128 + 2 * lane);
        float2 f1 = *(const float2*)(x + (size_t)s1v * 128 + 2 * lane);
        a0 += w0 * f0.x + w1 * f1.x;
        a1 += w0 * f0.y + w1 * f1.y;
    }
    if (k < en) {
        int s0 = esrc[k];
        float w0 = ew[k];
        float2 f0 = *(const float2*)(x + (size_t)s0 * 128 + 2 * lane);
        a0 += w0 * f0.x;
        a1 += w0 * f0.y;
    }

    // LayerNorm over the 128 features held as (a0,a1) across 64 lanes
    float s = a0 + a1;
#pragma unroll
    for (int off = 32; off; off >>= 1) s += __shfl_xor(s, off);
    float mu = s * (1.0f / 128.0f);
    float d0 = a0 - mu, d1 = a1 - mu;
    float q = d0 * d0 + d1 * d1;
#pragma unroll
    for (int off = 32; off; off >>= 1) q += __shfl_xor(q, off);
    float rstd = rsqrtf(q * (1.0f / 128.0f) + 1e-5f);
    float g0 = gamma[2 * lane], g1 = gamma[2 * lane + 1];
    float e0 = beta[2 * lane],  e1 = beta[2 * lane + 1];
    float2 o;
    o.x = d0 * rstd * g0 + e0;
    o.y = d1 * rstd * g1 + e1;
    *(float2*)(out + (size_t)row * 128 + 2 * lane) = o;
}

extern "C" void kernel_launch(void* const* d_in, const int* in_sizes, int n_in,
                              void* d_out, int out_size, void* d_ws, size_t ws_size,
                              hipStream_t stream) {
    const float* x     = (const float*)d_in[0];
    const int*   ei    = (const int*)d_in[1];
    const float* W1    = (const float*)d_in[2];
    const float* b1    = (const float*)d_in[3];
    const float* W2    = (const float*)d_in[4];
    const float* b2    = (const float*)d_in[5];
    const float* gamma = (const float*)d_in[6];
    const float* beta  = (const float*)d_in[7];
    float* out = (float*)d_out;

    const int N = in_sizes[0] / 128;   // 50000
    const int E = in_sizes[1] / 2;     // 800000
    const int NB = (N + 255) / 256;    // 196 scan blocks (<=256 required)

    // ---- workspace layout (bytes, 256-aligned slices) ----
    char* w = (char*)d_ws;
    size_t off = 0;
    auto alloc = [&](size_t bytes) {
        char* p = w + off;
        off = (off + bytes + 255) & ~(size_t)255;
        return p;
    };
    unsigned short* Bt       = (unsigned short*)alloc(256 * 128 * 2);     // 64 KB
    unsigned short* UV       = (unsigned short*)alloc((size_t)N * 256 * 2); // 25.6 MB
    int*            rowstart = (int*)alloc((size_t)(N + 1) * 4);          // deg -> rowstart
    int*            cursor   = (int*)alloc((size_t)N * 4);
    int*            bsum     = (int*)alloc(256 * 4);
    int*            esrc     = (int*)alloc((size_t)E * 4);                 // 3.2 MB
    float*          ew       = (float*)alloc((size_t)E * 4);               // 3.2 MB

    hipMemsetAsync(rowstart, 0, (size_t)(N + 1) * 4, stream);

    k_pack<<<128, 256, 0, stream>>>(W1, Bt);

    dim3 ggrid((N + 63) / 64, 4);
    k_gemm<<<ggrid, 256, 0, stream>>>(x, Bt, UV, N);

    k_hist<<<(E + 255) / 256, 256, 0, stream>>>(ei, rowstart, E);
    k_scan1<<<NB, 256, 0, stream>>>(rowstart, bsum, N);
    k_scan2<<<1, 256, 0, stream>>>(bsum, NB);
    k_scan3<<<NB, 256, 0, stream>>>(rowstart, bsum, cursor, N, E);

    k_wsc<<<2048, 256, 0, stream>>>(ei, UV, b1, W2, b2, cursor, esrc, ew, E);

    k_aggln<<<(N + 3) / 4, 256, 0, stream>>>(x, rowstart, esrc, ew, gamma, beta, out, N);
}

// Round 3
// 241.703 us; speedup vs baseline: 3.0370x; 1.2103x over previous
//
#include <hip/hip_runtime.h>

// ---------- helpers ----------
static __device__ __forceinline__ unsigned short f2bf(float f) {
    union { float f; unsigned int u; } c; c.f = f;
    unsigned int u = c.u;
    return (unsigned short)((u + 0x7FFFu + ((u >> 16) & 1u)) >> 16);  // RNE
}
static __device__ __forceinline__ float bflo(unsigned int uu) {
    union { unsigned int u; float f; } c; c.u = uu << 16; return c.f;
}
static __device__ __forceinline__ float bfhi(unsigned int uu) {
    union { unsigned int u; float f; } c; c.u = uu & 0xffff0000u; return c.f;
}

typedef __bf16 bf16x8 __attribute__((ext_vector_type(8)));
typedef float  f32x4  __attribute__((ext_vector_type(4)));

// ---------- pack W1 [256][128] f32 -> Bt [256][128] bf16 ----------
__global__ void k_pack(const float* __restrict__ W1, unsigned short* __restrict__ Bt) {
    int idx = blockIdx.x * blockDim.x + threadIdx.x;   // 32768 total
    int j = idx >> 7, k = idx & 127;
    int r = (j < 128) ? k : (128 + k);
    int c = j & 127;
    Bt[idx] = f2bf(W1[r * 128 + c]);
}

// ---------- GEMM: UV[M][256] = x[M][128] @ Bt^T (+b1 fold on v-half) ----------
__global__ __launch_bounds__(256) void k_gemm(const float* __restrict__ x,
                                              const unsigned short* __restrict__ Bt,
                                              const float* __restrict__ b1,
                                              unsigned short* __restrict__ UV, int M) {
    int wave = threadIdx.x >> 6, lane = threadIdx.x & 63;
    int row0 = blockIdx.x * 64 + wave * 16;
    int col0 = blockIdx.y * 64;
    int lr = lane & 15;
    int lk = (lane >> 4) << 3;

    f32x4 acc[4] = {};
    int arow = row0 + lr;
    bool in = (arow < M);
    const float* xr = x + (size_t)arow * 128;

#pragma unroll
    for (int kk = 0; kk < 4; ++kk) {
        int k = kk * 32 + lk;
        union { bf16x8 v; unsigned short u[8]; } ua;
        if (in) {
            float4 f0 = *(const float4*)(xr + k);
            float4 f1 = *(const float4*)(xr + k + 4);
            ua.u[0] = f2bf(f0.x); ua.u[1] = f2bf(f0.y);
            ua.u[2] = f2bf(f0.z); ua.u[3] = f2bf(f0.w);
            ua.u[4] = f2bf(f1.x); ua.u[5] = f2bf(f1.y);
            ua.u[6] = f2bf(f1.z); ua.u[7] = f2bf(f1.w);
        } else {
#pragma unroll
            for (int i = 0; i < 8; ++i) ua.u[i] = 0;
        }
#pragma unroll
        for (int nf = 0; nf < 4; ++nf) {
            int col = col0 + nf * 16 + lr;
            bf16x8 b = *(const bf16x8*)(Bt + col * 128 + k);
            acc[nf] = __builtin_amdgcn_mfma_f32_16x16x32_bf16(ua.v, b, acc[nf], 0, 0, 0);
        }
    }
    int rb = row0 + ((lane >> 4) << 2);
#pragma unroll
    for (int nf = 0; nf < 4; ++nf) {
        int feat = col0 + nf * 16 + lr;
        float bias = (feat >= 128) ? b1[feat - 128] : 0.0f;   // fold b1 into v-half
#pragma unroll
        for (int r = 0; r < 4; ++r) {
            int node = rb + r;
            if (node < M) UV[(size_t)node * 256 + feat] = f2bf(acc[nf][r] + bias);
        }
    }
}

// ---------- histogram of targets ----------
__global__ void k_hist(const int* __restrict__ ei, int* __restrict__ deg, int E) {
    int e = blockIdx.x * blockDim.x + threadIdx.x;
    if (e < E) atomicAdd(deg + ei[E + e], 1);
}

// ---------- scan stage 1 ----------
__global__ void k_scan1(int* __restrict__ a, int* __restrict__ bsum, int N) {
    __shared__ int s0[256], s1[256];
    int tid = threadIdx.x;
    int n = blockIdx.x * 256 + tid;
    int v = (n < N) ? a[n] : 0;
    s0[tid] = v;
    __syncthreads();
    int* cur = s0; int* nxt = s1;
#pragma unroll
    for (int off = 1; off < 256; off <<= 1) {
        int val = cur[tid];
        if (tid >= off) val += cur[tid - off];
        nxt[tid] = val;
        __syncthreads();
        int* t = cur; cur = nxt; nxt = t;
    }
    if (n < N) a[n] = cur[tid] - v;
    if (tid == 255) bsum[blockIdx.x] = cur[255];
}

// ---------- scan stage 2 ----------
__global__ void k_scan2(int* __restrict__ bsum, int nb) {
    __shared__ int s0[256], s1[256];
    int tid = threadIdx.x;
    int v = (tid < nb) ? bsum[tid] : 0;
    s0[tid] = v;
    __syncthreads();
    int* cur = s0; int* nxt = s1;
#pragma unroll
    for (int off = 1; off < 256; off <<= 1) {
        int val = cur[tid];
        if (tid >= off) val += cur[tid - off];
        nxt[tid] = val;
        __syncthreads();
        int* t = cur; cur = nxt; nxt = t;
    }
    if (tid < nb) bsum[tid] = cur[tid] - v;
}

// ---------- scan stage 3 ----------
__global__ void k_scan3(int* __restrict__ rowstart, const int* __restrict__ bsum,
                        int* __restrict__ cursor, int N, int E) {
    int n = blockIdx.x * 256 + threadIdx.x;
    if (n < N) {
        int r = rowstart[n] + bsum[n >> 8];
        rowstart[n] = r;
        cursor[n] = r;
    }
    if (n == 0) rowstart[N] = E;
}

// ---------- edge weights + bucket scatter: 8 edges/wave, 8 lanes/edge ----------
__global__ __launch_bounds__(256) void k_wsc(const int* __restrict__ ei,
                                             const unsigned short* __restrict__ UV,
                                             const float* __restrict__ W2,
                                             const float* __restrict__ b2,
                                             int* __restrict__ cursor,
                                             int* __restrict__ esrc,
                                             float* __restrict__ ew, int E) {
    int lane = threadIdx.x & 63;
    int wid  = (blockIdx.x * blockDim.x + threadIdx.x) >> 6;
    int nw   = (gridDim.x * blockDim.x) >> 6;
    int el = lane & 7;        // edge slot within wave
    int q  = lane >> 3;       // feature group: feats [16q, 16q+16)

    float w2r[16];
#pragma unroll
    for (int i = 0; i < 16; ++i) w2r[i] = W2[16 * q + i];
    float b2s = b2[0];

    for (int e0 = wid * 8; e0 < E; e0 += nw * 8) {
        int e = e0 + el;
        bool val = (e < E);
        int s = val ? ei[e]     : 0;
        int t = val ? ei[E + e] : 0;

        const unsigned short* up = UV + (size_t)s * 256 + 16 * q;
        const unsigned short* vp = UV + (size_t)t * 256 + 128 + 16 * q;
        uint4 ua = *(const uint4*)up;          // feats 16q+0..7  (u)
        uint4 ub = *(const uint4*)(up + 8);    // feats 16q+8..15 (u)
        uint4 va = *(const uint4*)vp;          // (v + b1 already folded)
        uint4 vb = *(const uint4*)(vp + 8);

        float p = 0.0f;
        p = fmaf(fmaxf(bflo(ua.x) + bflo(va.x), 0.f), w2r[0],  p);
        p = fmaf(fmaxf(bfhi(ua.x) + bfhi(va.x), 0.f), w2r[1],  p);
        p = fmaf(fmaxf(bflo(ua.y) + bflo(va.y), 0.f), w2r[2],  p);
        p = fmaf(fmaxf(bfhi(ua.y) + bfhi(va.y), 0.f), w2r[3],  p);
        p = fmaf(fmaxf(bflo(ua.z) + bflo(va.z), 0.f), w2r[4],  p);
        p = fmaf(fmaxf(bfhi(ua.z) + bfhi(va.z), 0.f), w2r[5],  p);
        p = fmaf(fmaxf(bflo(ua.w) + bflo(va.w), 0.f), w2r[6],  p);
        p = fmaf(fmaxf(bfhi(ua.w) + bfhi(va.w), 0.f), w2r[7],  p);
        p = fmaf(fmaxf(bflo(ub.x) + bflo(vb.x), 0.f), w2r[8],  p);
        p = fmaf(fmaxf(bfhi(ub.x) + bfhi(vb.x), 0.f), w2r[9],  p);
        p = fmaf(fmaxf(bflo(ub.y) + bflo(vb.y), 0.f), w2r[10], p);
        p = fmaf(fmaxf(bfhi(ub.y) + bfhi(vb.y), 0.f), w2r[11], p);
        p = fmaf(fmaxf(bflo(ub.z) + bflo(vb.z), 0.f), w2r[12], p);
        p = fmaf(fmaxf(bfhi(ub.z) + bfhi(vb.z), 0.f), w2r[13], p);
        p = fmaf(fmaxf(bflo(ub.w) + bflo(vb.w), 0.f), w2r[14], p);
        p = fmaf(fmaxf(bfhi(ub.w) + bfhi(vb.w), 0.f), w2r[15], p);

        // reduce across the 8 feature-groups (lane stride 8)
        p += __shfl_xor(p, 8);
        p += __shfl_xor(p, 16);
        p += __shfl_xor(p, 32);

        float w = 1.0f / (1.0f + __expf(-(p + b2s)));

        if ((lane < 8) && val) {
            int pos = atomicAdd(cursor + t, 1);
            esrc[pos] = s;
            ew[pos]   = w;
        }
    }
}

// ---------- gather-aggregate + fused LayerNorm: one wave per node, ILP-4 ----------
__global__ __launch_bounds__(256) void k_aggln(const float* __restrict__ x,
                                               const int* __restrict__ rowstart,
                                               const int* __restrict__ esrc,
                                               const float* __restrict__ ew,
                                               const float* __restrict__ gamma,
                                               const float* __restrict__ beta,
                                               float* __restrict__ out, int N) {
    int row = blockIdx.x * 4 + (threadIdx.x >> 6);
    if (row >= N) return;
    int lane = threadIdx.x & 63;

    int st = rowstart[row];
    int en = rowstart[row + 1];

    const float2* xb = (const float2*)x;
    float2 xx = xb[(size_t)row * 64 + lane];
    float a00 = xx.x, a01 = xx.y;
    float a10 = 0.f, a11 = 0.f, a20 = 0.f, a21 = 0.f, a30 = 0.f, a31 = 0.f;

    int k = st;
    for (; k + 4 <= en; k += 4) {
        int s0 = esrc[k], s1 = esrc[k + 1], s2 = esrc[k + 2], s3 = esrc[k + 3];
        float w0 = ew[k], w1 = ew[k + 1], w2 = ew[k + 2], w3 = ew[k + 3];
        float2 f0 = xb[(size_t)s0 * 64 + lane];
        float2 f1 = xb[(size_t)s1 * 64 + lane];
        float2 f2 = xb[(size_t)s2 * 64 + lane];
        float2 f3 = xb[(size_t)s3 * 64 + lane];
        a00 = fmaf(w0, f0.x, a00); a01 = fmaf(w0, f0.y, a01);
        a10 = fmaf(w1, f1.x, a10); a11 = fmaf(w1, f1.y, a11);
        a20 = fmaf(w2, f2.x, a20); a21 = fmaf(w2, f2.y, a21);
        a30 = fmaf(w3, f3.x, a30); a31 = fmaf(w3, f3.y, a31);
    }
    for (; k < en; ++k) {
        int s0 = esrc[k];
        float w0 = ew[k];
        float2 f0 = xb[(size_t)s0 * 64 + lane];
        a00 = fmaf(w0, f0.x, a00); a01 = fmaf(w0, f0.y, a01);
    }
    float a0 = (a00 + a20) + (a10 + a30);
    float a1 = (a01 + a21) + (a11 + a31);

    // LayerNorm over 128 features held as (a0,a1) across 64 lanes
    float s = a0 + a1;
#pragma unroll
    for (int off = 32; off; off >>= 1) s += __shfl_xor(s, off);
    float mu = s * (1.0f / 128.0f);
    float d0 = a0 - mu, d1 = a1 - mu;
    float q = d0 * d0 + d1 * d1;
#pragma unroll
    for (int off = 32; off; off >>= 1) q += __shfl_xor(q, off);
    float rstd = rsqrtf(q * (1.0f / 128.0f) + 1e-5f);
    float g0 = gamma[2 * lane], g1 = gamma[2 * lane + 1];
    float e0 = beta[2 * lane],  e1 = beta[2 * lane + 1];
    float2 o;
    o.x = d0 * rstd * g0 + e0;
    o.y = d1 * rstd * g1 + e1;
    *(float2*)(out + (size_t)row * 128 + 2 * lane) = o;
}

extern "C" void kernel_launch(void* const* d_in, const int* in_sizes, int n_in,
                              void* d_out, int out_size, void* d_ws, size_t ws_size,
                              hipStream_t stream) {
    const float* x     = (const float*)d_in[0];
    const int*   ei    = (const int*)d_in[1];
    const float* W1    = (const float*)d_in[2];
    const float* b1    = (const float*)d_in[3];
    const float* W2    = (const float*)d_in[4];
    const float* b2    = (const float*)d_in[5];
    const float* gamma = (const float*)d_in[6];
    const float* beta  = (const float*)d_in[7];
    float* out = (float*)d_out;

    const int N = in_sizes[0] / 128;   // 50000
    const int E = in_sizes[1] / 2;     // 800000
    const int NB = (N + 255) / 256;    // 196 scan blocks (<=256 required)

    // ---- workspace layout ----
    char* w = (char*)d_ws;
    size_t off = 0;
    auto alloc = [&](size_t bytes) {
        char* p = w + off;
        off = (off + bytes + 255) & ~(size_t)255;
        return p;
    };
    unsigned short* Bt       = (unsigned short*)alloc(256 * 128 * 2);
    unsigned short* UV       = (unsigned short*)alloc((size_t)N * 256 * 2);
    int*            rowstart = (int*)alloc((size_t)(N + 1) * 4);
    int*            cursor   = (int*)alloc((size_t)N * 4);
    int*            bsum     = (int*)alloc(256 * 4);
    int*            esrc     = (int*)alloc((size_t)E * 4);
    float*          ew       = (float*)alloc((size_t)E * 4);

    hipMemsetAsync(rowstart, 0, (size_t)(N + 1) * 4, stream);

    k_pack<<<128, 256, 0, stream>>>(W1, Bt);

    dim3 ggrid((N + 63) / 64, 4);
    k_gemm<<<ggrid, 256, 0, stream>>>(x, Bt, b1, UV, N);

    k_hist<<<(E + 255) / 256, 256, 0, stream>>>(ei, rowstart, E);
    k_scan1<<<NB, 256, 0, stream>>>(rowstart, bsum, N);
    k_scan2<<<1, 256, 0, stream>>>(bsum, NB);
    k_scan3<<<NB, 256, 0, stream>>>(rowstart, bsum, cursor, N, E);

    k_wsc<<<2048, 256, 0, stream>>>(ei, UV, W2, b2, cursor, esrc, ew, E);

    k_aggln<<<(N + 3) / 4, 256, 0, stream>>>(x, rowstart, esrc, ew, gamma, beta, out, N);
}

// Round 4
// 224.229 us; speedup vs baseline: 3.2737x; 1.0779x over previous
//
#include <hip/hip_runtime.h>

// ---------- helpers ----------
static __device__ __forceinline__ unsigned short f2bf(float f) {
    union { float f; unsigned int u; } c; c.f = f;
    unsigned int u = c.u;
    return (unsigned short)((u + 0x7FFFu + ((u >> 16) & 1u)) >> 16);  // RNE
}
static __device__ __forceinline__ float bflo(unsigned int uu) {
    union { unsigned int u; float f; } c; c.u = uu << 16; return c.f;
}
static __device__ __forceinline__ float bfhi(unsigned int uu) {
    union { unsigned int u; float f; } c; c.u = uu & 0xffff0000u; return c.f;
}

typedef __bf16 bf16x8 __attribute__((ext_vector_type(8)));
typedef float  f32x4  __attribute__((ext_vector_type(4)));

// ---------- pack W1 [256][128] f32 -> Bt [256][128] bf16 ----------
__global__ void k_pack(const float* __restrict__ W1, unsigned short* __restrict__ Bt) {
    int idx = blockIdx.x * blockDim.x + threadIdx.x;   // 32768 total
    int j = idx >> 7, k = idx & 127;
    int r = (j < 128) ? k : (128 + k);
    int c = j & 127;
    Bt[idx] = f2bf(W1[r * 128 + c]);
}

// ---------- GEMM: UV[M][256] = x[M][128] @ Bt^T (+b1 fold on v-half) ----------
// blockIdx.y==0 waves also emit XB[M][128] = bf16(x) as a free byproduct.
__global__ __launch_bounds__(256) void k_gemm(const float* __restrict__ x,
                                              const unsigned short* __restrict__ Bt,
                                              const float* __restrict__ b1,
                                              unsigned short* __restrict__ UV,
                                              unsigned short* __restrict__ XB, int M) {
    int wave = threadIdx.x >> 6, lane = threadIdx.x & 63;
    int row0 = blockIdx.x * 64 + wave * 16;
    int col0 = blockIdx.y * 64;
    int lr = lane & 15;
    int lk = (lane >> 4) << 3;

    f32x4 acc[4] = {};
    int arow = row0 + lr;
    bool in = (arow < M);
    const float* xr = x + (size_t)arow * 128;
    bool emit_xb = (XB != nullptr) && (blockIdx.y == 0);

#pragma unroll
    for (int kk = 0; kk < 4; ++kk) {
        int k = kk * 32 + lk;
        union { bf16x8 v; unsigned short u[8]; } ua;
        if (in) {
            float4 f0 = *(const float4*)(xr + k);
            float4 f1 = *(const float4*)(xr + k + 4);
            ua.u[0] = f2bf(f0.x); ua.u[1] = f2bf(f0.y);
            ua.u[2] = f2bf(f0.z); ua.u[3] = f2bf(f0.w);
            ua.u[4] = f2bf(f1.x); ua.u[5] = f2bf(f1.y);
            ua.u[6] = f2bf(f1.z); ua.u[7] = f2bf(f1.w);
        } else {
#pragma unroll
            for (int i = 0; i < 8; ++i) ua.u[i] = 0;
        }
        if (emit_xb && in) *(bf16x8*)(XB + (size_t)arow * 128 + k) = ua.v;
#pragma unroll
        for (int nf = 0; nf < 4; ++nf) {
            int col = col0 + nf * 16 + lr;
            bf16x8 b = *(const bf16x8*)(Bt + col * 128 + k);
            acc[nf] = __builtin_amdgcn_mfma_f32_16x16x32_bf16(ua.v, b, acc[nf], 0, 0, 0);
        }
    }
    int rb = row0 + ((lane >> 4) << 2);
#pragma unroll
    for (int nf = 0; nf < 4; ++nf) {
        int feat = col0 + nf * 16 + lr;
        float bias = (feat >= 128) ? b1[feat - 128] : 0.0f;   // fold b1 into v-half
#pragma unroll
        for (int r = 0; r < 4; ++r) {
            int node = rb + r;
            if (node < M) UV[(size_t)node * 256 + feat] = f2bf(acc[nf][r] + bias);
        }
    }
}

// ---------- histogram of targets ----------
__global__ void k_hist(const int* __restrict__ ei, int* __restrict__ deg, int E) {
    int e = blockIdx.x * blockDim.x + threadIdx.x;
    if (e < E) atomicAdd(deg + ei[E + e], 1);
}

// ---------- scan stage 1 ----------
__global__ void k_scan1(int* __restrict__ a, int* __restrict__ bsum, int N) {
    __shared__ int s0[256], s1[256];
    int tid = threadIdx.x;
    int n = blockIdx.x * 256 + tid;
    int v = (n < N) ? a[n] : 0;
    s0[tid] = v;
    __syncthreads();
    int* cur = s0; int* nxt = s1;
#pragma unroll
    for (int off = 1; off < 256; off <<= 1) {
        int val = cur[tid];
        if (tid >= off) val += cur[tid - off];
        nxt[tid] = val;
        __syncthreads();
        int* t = cur; cur = nxt; nxt = t;
    }
    if (n < N) a[n] = cur[tid] - v;
    if (tid == 255) bsum[blockIdx.x] = cur[255];
}

// ---------- scan stage 2 ----------
__global__ void k_scan2(int* __restrict__ bsum, int nb) {
    __shared__ int s0[256], s1[256];
    int tid = threadIdx.x;
    int v = (tid < nb) ? bsum[tid] : 0;
    s0[tid] = v;
    __syncthreads();
    int* cur = s0; int* nxt = s1;
#pragma unroll
    for (int off = 1; off < 256; off <<= 1) {
        int val = cur[tid];
        if (tid >= off) val += cur[tid - off];
        nxt[tid] = val;
        __syncthreads();
        int* t = cur; cur = nxt; nxt = t;
    }
    if (tid < nb) bsum[tid] = cur[tid] - v;
}

// ---------- scan stage 3 ----------
__global__ void k_scan3(int* __restrict__ rowstart, const int* __restrict__ bsum,
                        int* __restrict__ cursor, int N, int E) {
    int n = blockIdx.x * 256 + threadIdx.x;
    if (n < N) {
        int r = rowstart[n] + bsum[n >> 8];
        rowstart[n] = r;
        cursor[n] = r;
    }
    if (n == 0) rowstart[N] = E;
}

// ---------- CSR scatter: esrc[pos] = s, bucketed by target ----------
__global__ void k_scatter(const int* __restrict__ ei, int* __restrict__ cursor,
                          int* __restrict__ esrc, int E) {
    int e = blockIdx.x * blockDim.x + threadIdx.x;
    if (e < E) {
        int s = ei[e];
        int t = ei[E + e];
        int pos = atomicAdd(cursor + t, 1);
        esrc[pos] = s;
    }
}

// ---------- fused: per-target weights + aggregate + LayerNorm ----------
// One wave per node. Edge-group layout: 8 edges/wave, 8 lanes/edge, 16 feats/lane.
template <int USE_XB>
__global__ __launch_bounds__(256) void k_fused(const float* __restrict__ x,
                                               const unsigned short* __restrict__ UV,
                                               const unsigned short* __restrict__ XB,
                                               const int* __restrict__ rowstart,
                                               const int* __restrict__ esrc,
                                               const float* __restrict__ W2,
                                               const float* __restrict__ b2,
                                               const float* __restrict__ gamma,
                                               const float* __restrict__ beta,
                                               float* __restrict__ out, int N) {
    int row = blockIdx.x * 4 + (threadIdx.x >> 6);
    if (row >= N) return;
    int lane = threadIdx.x & 63;
    int el = lane & 7;        // edge slot
    int q  = lane >> 3;       // feature group: feats [16q, 16q+16)

    float w2r[16];
#pragma unroll
    for (int i = 0; i < 16; ++i) w2r[i] = W2[16 * q + i];
    float b2s = b2[0];

    // v_t (+b1 already folded), 16 feats for this lane's group, sequential load
    const unsigned short* vp = UV + (size_t)row * 256 + 128 + 16 * q;
    uint4 va = *(const uint4*)vp;
    uint4 vb = *(const uint4*)(vp + 8);
    float vf[16];
    vf[0]  = bflo(va.x); vf[1]  = bfhi(va.x);
    vf[2]  = bflo(va.y); vf[3]  = bfhi(va.y);
    vf[4]  = bflo(va.z); vf[5]  = bfhi(va.z);
    vf[6]  = bflo(va.w); vf[7]  = bfhi(va.w);
    vf[8]  = bflo(vb.x); vf[9]  = bfhi(vb.x);
    vf[10] = bflo(vb.y); vf[11] = bfhi(vb.y);
    vf[12] = bflo(vb.z); vf[13] = bfhi(vb.z);
    vf[14] = bflo(vb.w); vf[15] = bfhi(vb.w);

    int st = rowstart[row];
    int en = rowstart[row + 1];

    // residual: x[t] in f32 (sequential)
    float2 xx = *(const float2*)(x + (size_t)row * 128 + 2 * lane);
    float a0 = xx.x, a1 = xx.y;

    for (int g = st; g < en; g += 8) {
        int e = g + el;
        bool val = (e < en);
        int s = val ? esrc[e] : 0;

        const unsigned short* up = UV + (size_t)s * 256 + 16 * q;
        uint4 ua = *(const uint4*)up;
        uint4 ub = *(const uint4*)(up + 8);

        float p = 0.0f;
        p = fmaf(fmaxf(bflo(ua.x) + vf[0],  0.f), w2r[0],  p);
        p = fmaf(fmaxf(bfhi(ua.x) + vf[1],  0.f), w2r[1],  p);
        p = fmaf(fmaxf(bflo(ua.y) + vf[2],  0.f), w2r[2],  p);
        p = fmaf(fmaxf(bfhi(ua.y) + vf[3],  0.f), w2r[3],  p);
        p = fmaf(fmaxf(bflo(ua.z) + vf[4],  0.f), w2r[4],  p);
        p = fmaf(fmaxf(bfhi(ua.z) + vf[5],  0.f), w2r[5],  p);
        p = fmaf(fmaxf(bflo(ua.w) + vf[6],  0.f), w2r[6],  p);
        p = fmaf(fmaxf(bfhi(ua.w) + vf[7],  0.f), w2r[7],  p);
        p = fmaf(fmaxf(bflo(ub.x) + vf[8],  0.f), w2r[8],  p);
        p = fmaf(fmaxf(bfhi(ub.x) + vf[9],  0.f), w2r[9],  p);
        p = fmaf(fmaxf(bflo(ub.y) + vf[10], 0.f), w2r[10], p);
        p = fmaf(fmaxf(bfhi(ub.y) + vf[11], 0.f), w2r[11], p);
        p = fmaf(fmaxf(bflo(ub.z) + vf[12], 0.f), w2r[12], p);
        p = fmaf(fmaxf(bfhi(ub.z) + vf[13], 0.f), w2r[13], p);
        p = fmaf(fmaxf(bflo(ub.w) + vf[14], 0.f), w2r[14], p);
        p = fmaf(fmaxf(bfhi(ub.w) + vf[15], 0.f), w2r[15], p);

        // reduce across the 8 feature groups (lane stride 8)
        p += __shfl_xor(p, 8);
        p += __shfl_xor(p, 16);
        p += __shfl_xor(p, 32);

        float w = val ? 1.0f / (1.0f + __expf(-(p + b2s))) : 0.0f;

        // aggregate the 8 edges of this group
#pragma unroll
        for (int j = 0; j < 8; ++j) {
            float wj = __shfl(w, j);
            int   sj = __shfl(s, j);
            if (USE_XB) {
                unsigned int xv = *(const unsigned int*)(XB + (size_t)sj * 128 + 2 * lane);
                a0 = fmaf(wj, bflo(xv), a0);
                a1 = fmaf(wj, bfhi(xv), a1);
            } else {
                float2 xf = *(const float2*)(x + (size_t)sj * 128 + 2 * lane);
                a0 = fmaf(wj, xf.x, a0);
                a1 = fmaf(wj, xf.y, a1);
            }
        }
    }

    // LayerNorm over 128 features held as (a0,a1) across 64 lanes
    float s = a0 + a1;
#pragma unroll
    for (int off = 32; off; off >>= 1) s += __shfl_xor(s, off);
    float mu = s * (1.0f / 128.0f);
    float d0 = a0 - mu, d1 = a1 - mu;
    float qq = d0 * d0 + d1 * d1;
#pragma unroll
    for (int off = 32; off; off >>= 1) qq += __shfl_xor(qq, off);
    float rstd = rsqrtf(qq * (1.0f / 128.0f) + 1e-5f);
    float2 gg = *(const float2*)(gamma + 2 * lane);
    float2 bb = *(const float2*)(beta + 2 * lane);
    float2 o;
    o.x = d0 * rstd * gg.x + bb.x;
    o.y = d1 * rstd * gg.y + bb.y;
    *(float2*)(out + (size_t)row * 128 + 2 * lane) = o;
}

extern "C" void kernel_launch(void* const* d_in, const int* in_sizes, int n_in,
                              void* d_out, int out_size, void* d_ws, size_t ws_size,
                              hipStream_t stream) {
    const float* x     = (const float*)d_in[0];
    const int*   ei    = (const int*)d_in[1];
    const float* W1    = (const float*)d_in[2];
    const float* b1    = (const float*)d_in[3];
    const float* W2    = (const float*)d_in[4];
    const float* b2    = (const float*)d_in[5];
    const float* gamma = (const float*)d_in[6];
    const float* beta  = (const float*)d_in[7];
    float* out = (float*)d_out;

    const int N = in_sizes[0] / 128;   // 50000
    const int E = in_sizes[1] / 2;     // 800000
    const int NB = (N + 255) / 256;    // 196 scan blocks (<=256 required)

    // ---- workspace layout ----
    char* w = (char*)d_ws;
    size_t off = 0;
    auto alloc = [&](size_t bytes) {
        char* p = w + off;
        off = (off + bytes + 255) & ~(size_t)255;
        return p;
    };
    unsigned short* Bt       = (unsigned short*)alloc(256 * 128 * 2);       // 64 KB
    unsigned short* UV       = (unsigned short*)alloc((size_t)N * 256 * 2); // 25.6 MB
    int*            rowstart = (int*)alloc((size_t)(N + 1) * 4);
    int*            cursor   = (int*)alloc((size_t)N * 4);
    int*            bsum     = (int*)alloc(256 * 4);
    int*            esrc     = (int*)alloc((size_t)E * 4);                  // 3.2 MB
    size_t off_noxb = off;
    unsigned short* XB       = (unsigned short*)alloc((size_t)N * 128 * 2); // 12.8 MB
    bool use_xb = (off <= ws_size);
    if (!use_xb) { XB = nullptr; off = off_noxb; }

    hipMemsetAsync(rowstart, 0, (size_t)(N + 1) * 4, stream);

    k_pack<<<128, 256, 0, stream>>>(W1, Bt);

    dim3 ggrid((N + 63) / 64, 4);
    k_gemm<<<ggrid, 256, 0, stream>>>(x, Bt, b1, UV, XB, N);

    k_hist<<<(E + 255) / 256, 256, 0, stream>>>(ei, rowstart, E);
    k_scan1<<<NB, 256, 0, stream>>>(rowstart, bsum, N);
    k_scan2<<<1, 256, 0, stream>>>(bsum, NB);
    k_scan3<<<NB, 256, 0, stream>>>(rowstart, bsum, cursor, N, E);

    k_scatter<<<(E + 255) / 256, 256, 0, stream>>>(ei, cursor, esrc, E);

    if (use_xb)
        k_fused<1><<<(N + 3) / 4, 256, 0, stream>>>(x, UV, XB, rowstart, esrc,
                                                    W2, b2, gamma, beta, out, N);
    else
        k_fused<0><<<(N + 3) / 4, 256, 0, stream>>>(x, UV, XB, rowstart, esrc,
                                                    W2, b2, gamma, beta, out, N);
}

// Round 5
// 190.470 us; speedup vs baseline: 3.8539x; 1.1772x over previous
//
#include <hip/hip_runtime.h>

// ---------- helpers ----------
static __device__ __forceinline__ unsigned short f2bf(float f) {
    union { float f; unsigned int u; } c; c.f = f;
    unsigned int u = c.u;
    return (unsigned short)((u + 0x7FFFu + ((u >> 16) & 1u)) >> 16);  // RNE
}
static __device__ __forceinline__ float bflo(unsigned int uu) {
    union { unsigned int u; float f; } c; c.u = uu << 16; return c.f;
}
static __device__ __forceinline__ float bfhi(unsigned int uu) {
    union { unsigned int u; float f; } c; c.u = uu & 0xffff0000u; return c.f;
}
static __device__ __forceinline__ unsigned char f2fp8(float f) {
    int enc = __builtin_amdgcn_cvt_pk_fp8_f32(f, f, 0, false);  // OCP e4m3 on gfx950
    return (unsigned char)(enc & 0xff);
}

typedef __bf16 bf16x8 __attribute__((ext_vector_type(8)));
typedef float  f32x4  __attribute__((ext_vector_type(4)));
typedef float  f32x2  __attribute__((ext_vector_type(2)));

// ---------- pack W1 -> Bt bf16 [256][128], and zero rowstart ----------
__global__ void k_pack(const float* __restrict__ W1, unsigned short* __restrict__ Bt,
                       int* __restrict__ rowstart, int N) {
    int idx = blockIdx.x * blockDim.x + threadIdx.x;
    if (idx < 256 * 128) {
        int j = idx >> 7, k = idx & 127;
        int r = (j < 128) ? k : (128 + k);
        int c = j & 127;
        Bt[idx] = f2bf(W1[r * 128 + c]);
    }
    if (idx <= N) rowstart[idx] = 0;
}

// ---------- one-pass GEMM: U[M][128] fp8, V[M][128] bf16 (+b1), XB[M][128] bf16
//            + fused target-histogram with rank recording ----------
__global__ __launch_bounds__(256) void k_gemm(const float* __restrict__ x,
                                              const unsigned short* __restrict__ Bt,
                                              const float* __restrict__ b1,
                                              unsigned char* __restrict__ U,
                                              unsigned short* __restrict__ V,
                                              unsigned short* __restrict__ XB,
                                              const int* __restrict__ ei,
                                              int* __restrict__ deg,
                                              int* __restrict__ rank,
                                              int M, int E) {
    int wave = threadIdx.x >> 6, lane = threadIdx.x & 63;
    int row0 = blockIdx.x * 64 + wave * 16;
    int lr = lane & 15;
    int lk = (lane >> 4) << 3;

    f32x4 acc[16];
#pragma unroll
    for (int i = 0; i < 16; ++i) acc[i] = (f32x4){0.f, 0.f, 0.f, 0.f};

    int arow = row0 + lr;
    bool in = (arow < M);
    const float* xr = x + (size_t)arow * 128;

#pragma unroll
    for (int kk = 0; kk < 4; ++kk) {
        int k = kk * 32 + lk;
        union { bf16x8 v; unsigned short u[8]; } ua;
        if (in) {
            float4 f0 = *(const float4*)(xr + k);
            float4 f1 = *(const float4*)(xr + k + 4);
            ua.u[0] = f2bf(f0.x); ua.u[1] = f2bf(f0.y);
            ua.u[2] = f2bf(f0.z); ua.u[3] = f2bf(f0.w);
            ua.u[4] = f2bf(f1.x); ua.u[5] = f2bf(f1.y);
            ua.u[6] = f2bf(f1.z); ua.u[7] = f2bf(f1.w);
            *(bf16x8*)(XB + (size_t)arow * 128 + k) = ua.v;  // bf16(x) byproduct
        } else {
#pragma unroll
            for (int i = 0; i < 8; ++i) ua.u[i] = 0;
        }
#pragma unroll
        for (int nf = 0; nf < 16; ++nf) {
            int col = nf * 16 + lr;
            bf16x8 b = *(const bf16x8*)(Bt + col * 128 + k);
            acc[nf] = __builtin_amdgcn_mfma_f32_16x16x32_bf16(ua.v, b, acc[nf], 0, 0, 0);
        }
    }
    // C/D: col = lane&15, row = (lane>>4)*4 + reg
    int rb = row0 + ((lane >> 4) << 2);
#pragma unroll
    for (int nf = 0; nf < 16; ++nf) {
        int feat = nf * 16 + lr;
        if (feat < 128) {
#pragma unroll
            for (int r = 0; r < 4; ++r) {
                int node = rb + r;
                if (node < M) U[(size_t)node * 128 + feat] = f2fp8(acc[nf][r]);
            }
        } else {
            float bias = b1[feat - 128];
#pragma unroll
            for (int r = 0; r < 4; ++r) {
                int node = rb + r;
                if (node < M) V[(size_t)node * 128 + (feat - 128)] = f2bf(acc[nf][r] + bias);
            }
        }
    }

    // fused histogram: rank[e] = old count of target
    int tid = blockIdx.x * blockDim.x + threadIdx.x;
    int nthreads = gridDim.x * blockDim.x;
    for (int e = tid; e < E; e += nthreads) {
        int t = ei[E + e];
        rank[e] = atomicAdd(deg + t, 1);
    }
}

// ---------- scan stage 1 ----------
__global__ void k_scan1(int* __restrict__ a, int* __restrict__ bsum, int N) {
    __shared__ int s0[256], s1[256];
    int tid = threadIdx.x;
    int n = blockIdx.x * 256 + tid;
    int v = (n < N) ? a[n] : 0;
    s0[tid] = v;
    __syncthreads();
    int* cur = s0; int* nxt = s1;
#pragma unroll
    for (int off = 1; off < 256; off <<= 1) {
        int val = cur[tid];
        if (tid >= off) val += cur[tid - off];
        nxt[tid] = val;
        __syncthreads();
        int* t = cur; cur = nxt; nxt = t;
    }
    if (n < N) a[n] = cur[tid] - v;
    if (tid == 255) bsum[blockIdx.x] = cur[255];
}

// ---------- scan stage 2 ----------
__global__ void k_scan2(int* __restrict__ bsum, int nb) {
    __shared__ int s0[256], s1[256];
    int tid = threadIdx.x;
    int v = (tid < nb) ? bsum[tid] : 0;
    s0[tid] = v;
    __syncthreads();
    int* cur = s0; int* nxt = s1;
#pragma unroll
    for (int off = 1; off < 256; off <<= 1) {
        int val = cur[tid];
        if (tid >= off) val += cur[tid - off];
        nxt[tid] = val;
        __syncthreads();
        int* t = cur; cur = nxt; nxt = t;
    }
    if (tid < nb) bsum[tid] = cur[tid] - v;
}

// ---------- scan stage 3 ----------
__global__ void k_scan3(int* __restrict__ rowstart, const int* __restrict__ bsum,
                        int N, int E) {
    int n = blockIdx.x * 256 + threadIdx.x;
    if (n < N) rowstart[n] = rowstart[n] + bsum[n >> 8];
    if (n == 0) rowstart[N] = E;
}

// ---------- CSR scatter (no atomics: pos = rowstart[t] + rank[e]) ----------
__global__ void k_scatter(const int* __restrict__ ei, const int* __restrict__ rowstart,
                          const int* __restrict__ rank, int* __restrict__ esrc, int E) {
    int e = blockIdx.x * blockDim.x + threadIdx.x;
    if (e < E) {
        int s = ei[e];
        int t = ei[E + e];
        esrc[rowstart[t] + rank[e]] = s;
    }
}

// ---------- fused: per-target weights + aggregate + LayerNorm ----------
// One wave per node. 8 edges/wave, 8 lanes/edge, 16 feats/lane.
template <int USE_XB>
__global__ __launch_bounds__(256) void k_fused(const float* __restrict__ x,
                                               const unsigned char* __restrict__ U,
                                               const unsigned short* __restrict__ V,
                                               const unsigned short* __restrict__ XB,
                                               const int* __restrict__ rowstart,
                                               const int* __restrict__ esrc,
                                               const float* __restrict__ W2,
                                               const float* __restrict__ b2,
                                               const float* __restrict__ gamma,
                                               const float* __restrict__ beta,
                                               float* __restrict__ out, int N) {
    int row = blockIdx.x * 4 + (threadIdx.x >> 6);
    if (row >= N) return;
    int lane = threadIdx.x & 63;
    int el = lane & 7;        // edge slot
    int q  = lane >> 3;       // feature group: feats [16q, 16q+16)

    float w2r[16];
#pragma unroll
    for (int i = 0; i < 16; ++i) w2r[i] = W2[16 * q + i];
    float b2s = b2[0];

    // v_t (+b1 folded), 16 feats, sequential bf16 load
    const unsigned short* vp = V + (size_t)row * 128 + 16 * q;
    uint4 va = *(const uint4*)vp;
    uint4 vb = *(const uint4*)(vp + 8);
    float vf[16];
    vf[0]  = bflo(va.x); vf[1]  = bfhi(va.x);
    vf[2]  = bflo(va.y); vf[3]  = bfhi(va.y);
    vf[4]  = bflo(va.z); vf[5]  = bfhi(va.z);
    vf[6]  = bflo(va.w); vf[7]  = bfhi(va.w);
    vf[8]  = bflo(vb.x); vf[9]  = bfhi(vb.x);
    vf[10] = bflo(vb.y); vf[11] = bfhi(vb.y);
    vf[12] = bflo(vb.z); vf[13] = bfhi(vb.z);
    vf[14] = bflo(vb.w); vf[15] = bfhi(vb.w);

    int st = rowstart[row];
    int en = rowstart[row + 1];

    // residual: x[t] in f32 (sequential)
    float2 xx = *(const float2*)(x + (size_t)row * 128 + 2 * lane);
    float a0 = xx.x, a1 = xx.y;

    for (int g = st; g < en; g += 8) {
        int e = g + el;
        bool val = (e < en);
        int s = val ? esrc[e] : 0;

        // u[s]: 16 fp8 feats = one uint4
        uint4 ua = *(const uint4*)(U + (size_t)s * 128 + 16 * q);
        f32x2 d0 = __builtin_amdgcn_cvt_pk_f32_fp8(ua.x, false);
        f32x2 d1 = __builtin_amdgcn_cvt_pk_f32_fp8(ua.x, true);
        f32x2 d2 = __builtin_amdgcn_cvt_pk_f32_fp8(ua.y, false);
        f32x2 d3 = __builtin_amdgcn_cvt_pk_f32_fp8(ua.y, true);
        f32x2 d4 = __builtin_amdgcn_cvt_pk_f32_fp8(ua.z, false);
        f32x2 d5 = __builtin_amdgcn_cvt_pk_f32_fp8(ua.z, true);
        f32x2 d6 = __builtin_amdgcn_cvt_pk_f32_fp8(ua.w, false);
        f32x2 d7 = __builtin_amdgcn_cvt_pk_f32_fp8(ua.w, true);

        float p = 0.0f;
        p = fmaf(fmaxf(d0.x + vf[0],  0.f), w2r[0],  p);
        p = fmaf(fmaxf(d0.y + vf[1],  0.f), w2r[1],  p);
        p = fmaf(fmaxf(d1.x + vf[2],  0.f), w2r[2],  p);
        p = fmaf(fmaxf(d1.y + vf[3],  0.f), w2r[3],  p);
        p = fmaf(fmaxf(d2.x + vf[4],  0.f), w2r[4],  p);
        p = fmaf(fmaxf(d2.y + vf[5],  0.f), w2r[5],  p);
        p = fmaf(fmaxf(d3.x + vf[6],  0.f), w2r[6],  p);
        p = fmaf(fmaxf(d3.y + vf[7],  0.f), w2r[7],  p);
        p = fmaf(fmaxf(d4.x + vf[8],  0.f), w2r[8],  p);
        p = fmaf(fmaxf(d4.y + vf[9],  0.f), w2r[9],  p);
        p = fmaf(fmaxf(d5.x + vf[10], 0.f), w2r[10], p);
        p = fmaf(fmaxf(d5.y + vf[11], 0.f), w2r[11], p);
        p = fmaf(fmaxf(d6.x + vf[12], 0.f), w2r[12], p);
        p = fmaf(fmaxf(d6.y + vf[13], 0.f), w2r[13], p);
        p = fmaf(fmaxf(d7.x + vf[14], 0.f), w2r[14], p);
        p = fmaf(fmaxf(d7.y + vf[15], 0.f), w2r[15], p);

        p += __shfl_xor(p, 8);
        p += __shfl_xor(p, 16);
        p += __shfl_xor(p, 32);

        float w = val ? 1.0f / (1.0f + __expf(-(p + b2s))) : 0.0f;

#pragma unroll
        for (int j = 0; j < 8; ++j) {
            float wj = __shfl(w, j);
            int   sj = __shfl(s, j);
            if (USE_XB) {
                unsigned int xv = *(const unsigned int*)(XB + (size_t)sj * 128 + 2 * lane);
                a0 = fmaf(wj, bflo(xv), a0);
                a1 = fmaf(wj, bfhi(xv), a1);
            } else {
                float2 xf = *(const float2*)(x + (size_t)sj * 128 + 2 * lane);
                a0 = fmaf(wj, xf.x, a0);
                a1 = fmaf(wj, xf.y, a1);
            }
        }
    }

    // LayerNorm
    float s = a0 + a1;
#pragma unroll
    for (int off = 32; off; off >>= 1) s += __shfl_xor(s, off);
    float mu = s * (1.0f / 128.0f);
    float d0v = a0 - mu, d1v = a1 - mu;
    float qq = d0v * d0v + d1v * d1v;
#pragma unroll
    for (int off = 32; off; off >>= 1) qq += __shfl_xor(qq, off);
    float rstd = rsqrtf(qq * (1.0f / 128.0f) + 1e-5f);
    float2 gg = *(const float2*)(gamma + 2 * lane);
    float2 bb = *(const float2*)(beta + 2 * lane);
    float2 o;
    o.x = d0v * rstd * gg.x + bb.x;
    o.y = d1v * rstd * gg.y + bb.y;
    *(float2*)(out + (size_t)row * 128 + 2 * lane) = o;
}

extern "C" void kernel_launch(void* const* d_in, const int* in_sizes, int n_in,
                              void* d_out, int out_size, void* d_ws, size_t ws_size,
                              hipStream_t stream) {
    const float* x     = (const float*)d_in[0];
    const int*   ei    = (const int*)d_in[1];
    const float* W1    = (const float*)d_in[2];
    const float* b1    = (const float*)d_in[3];
    const float* W2    = (const float*)d_in[4];
    const float* b2    = (const float*)d_in[5];
    const float* gamma = (const float*)d_in[6];
    const float* beta  = (const float*)d_in[7];
    float* out = (float*)d_out;

    const int N = in_sizes[0] / 128;   // 50000
    const int E = in_sizes[1] / 2;     // 800000
    const int NB = (N + 255) / 256;    // 196 scan blocks (<=256 required)

    // ---- workspace layout ----
    char* w = (char*)d_ws;
    size_t off = 0;
    auto alloc = [&](size_t bytes) {
        char* p = w + off;
        off = (off + bytes + 255) & ~(size_t)255;
        return p;
    };
    unsigned short* Bt       = (unsigned short*)alloc(256 * 128 * 2);       // 64 KB
    unsigned char*  U        = (unsigned char*)alloc((size_t)N * 128);      // 6.4 MB
    unsigned short* V        = (unsigned short*)alloc((size_t)N * 128 * 2); // 12.8 MB
    int*            rowstart = (int*)alloc((size_t)(N + 1) * 4);
    int*            bsum     = (int*)alloc(256 * 4);
    int*            rank     = (int*)alloc((size_t)E * 4);                  // 3.2 MB
    int*            esrc     = (int*)alloc((size_t)E * 4);                  // 3.2 MB
    size_t off_noxb = off;
    unsigned short* XB       = (unsigned short*)alloc((size_t)N * 128 * 2); // 12.8 MB
    bool use_xb = (off <= ws_size);
    if (!use_xb) { XB = nullptr; off = off_noxb; }

    int PB = (N + 256) / 256;          // covers rowstart zeroing
    if (PB < 128) PB = 128;            // covers Bt pack
    k_pack<<<PB, 256, 0, stream>>>(W1, Bt, rowstart, N);

    k_gemm<<<(N + 63) / 64, 256, 0, stream>>>(x, Bt, b1, U, V, XB, ei,
                                              rowstart, rank, N, E);

    k_scan1<<<NB, 256, 0, stream>>>(rowstart, bsum, N);
    k_scan2<<<1, 256, 0, stream>>>(bsum, NB);
    k_scan3<<<NB, 256, 0, stream>>>(rowstart, bsum, N, E);

    k_scatter<<<(E + 255) / 256, 256, 0, stream>>>(ei, rowstart, rank, esrc, E);

    if (use_xb)
        k_fused<1><<<(N + 3) / 4, 256, 0, stream>>>(x, U, V, XB, rowstart, esrc,
                                                    W2, b2, gamma, beta, out, N);
    else
        k_fused<0><<<(N + 3) / 4, 256, 0, stream>>>(x, U, V, XB, rowstart, esrc,
                                                    W2, b2, gamma, beta, out, N);
}

// Round 6
// 171.257 us; speedup vs baseline: 4.2863x; 1.1122x over previous
//
#include <hip/hip_runtime.h>

// ---------- helpers ----------
static __device__ __forceinline__ unsigned short f2bf(float f) {
    union { float f; unsigned int u; } c; c.f = f;
    unsigned int u = c.u;
    return (unsigned short)((u + 0x7FFFu + ((u >> 16) & 1u)) >> 16);  // RNE
}
static __device__ __forceinline__ float bflo(unsigned int uu) {
    union { unsigned int u; float f; } c; c.u = uu << 16; return c.f;
}
static __device__ __forceinline__ float bfhi(unsigned int uu) {
    union { unsigned int u; float f; } c; c.u = uu & 0xffff0000u; return c.f;
}
static __device__ __forceinline__ unsigned char f2fp8(float f) {
    int enc = __builtin_amdgcn_cvt_pk_fp8_f32(f, f, 0, false);  // OCP e4m3 on gfx950
    return (unsigned char)(enc & 0xff);
}

typedef __bf16 bf16x8 __attribute__((ext_vector_type(8)));
typedef float  f32x4  __attribute__((ext_vector_type(4)));
typedef float  f32x2  __attribute__((ext_vector_type(2)));

// ---------- pack W1 -> Bt bf16 [256][128], and zero rowstart ----------
__global__ void k_pack(const float* __restrict__ W1, unsigned short* __restrict__ Bt,
                       int* __restrict__ rowstart, int N) {
    int idx = blockIdx.x * blockDim.x + threadIdx.x;
    if (idx < 256 * 128) {
        int j = idx >> 7, k = idx & 127;
        int r = (j < 128) ? k : (128 + k);
        int c = j & 127;
        Bt[idx] = f2bf(W1[r * 128 + c]);
    }
    if (idx <= N) rowstart[idx] = 0;
}

// ---------- GEMM (R4-proven shape): grid (ceil(M/64), 4), acc[4]/wave ----------
// y=0,1 -> U[M][128] fp8 (feats 0..127); y=2,3 -> V[M][128] bf16 + b1 fold.
// y==0 also emits XB[M][128] = bf16(x).
__global__ __launch_bounds__(256) void k_gemm(const float* __restrict__ x,
                                              const unsigned short* __restrict__ Bt,
                                              const float* __restrict__ b1,
                                              unsigned char* __restrict__ U,
                                              unsigned short* __restrict__ V,
                                              unsigned short* __restrict__ XB, int M) {
    int wave = threadIdx.x >> 6, lane = threadIdx.x & 63;
    int row0 = blockIdx.x * 64 + wave * 16;
    int col0 = blockIdx.y * 64;
    int lr = lane & 15;
    int lk = (lane >> 4) << 3;

    f32x4 acc[4] = {};
    int arow = row0 + lr;
    bool in = (arow < M);
    const float* xr = x + (size_t)arow * 128;
    bool emit_xb = (blockIdx.y == 0);

#pragma unroll
    for (int kk = 0; kk < 4; ++kk) {
        int k = kk * 32 + lk;
        union { bf16x8 v; unsigned short u[8]; } ua;
        if (in) {
            float4 f0 = *(const float4*)(xr + k);
            float4 f1 = *(const float4*)(xr + k + 4);
            ua.u[0] = f2bf(f0.x); ua.u[1] = f2bf(f0.y);
            ua.u[2] = f2bf(f0.z); ua.u[3] = f2bf(f0.w);
            ua.u[4] = f2bf(f1.x); ua.u[5] = f2bf(f1.y);
            ua.u[6] = f2bf(f1.z); ua.u[7] = f2bf(f1.w);
        } else {
#pragma unroll
            for (int i = 0; i < 8; ++i) ua.u[i] = 0;
        }
        if (emit_xb && in) *(bf16x8*)(XB + (size_t)arow * 128 + k) = ua.v;
#pragma unroll
        for (int nf = 0; nf < 4; ++nf) {
            int col = col0 + nf * 16 + lr;
            bf16x8 b = *(const bf16x8*)(Bt + col * 128 + k);
            acc[nf] = __builtin_amdgcn_mfma_f32_16x16x32_bf16(ua.v, b, acc[nf], 0, 0, 0);
        }
    }
    // C/D: col = lane&15, row = (lane>>4)*4 + reg
    int rb = row0 + ((lane >> 4) << 2);
    if (col0 < 128) {
#pragma unroll
        for (int nf = 0; nf < 4; ++nf) {
            int feat = col0 + nf * 16 + lr;
#pragma unroll
            for (int r = 0; r < 4; ++r) {
                int node = rb + r;
                if (node < M) U[(size_t)node * 128 + feat] = f2fp8(acc[nf][r]);
            }
        }
    } else {
#pragma unroll
        for (int nf = 0; nf < 4; ++nf) {
            int feat = col0 + nf * 16 + lr - 128;
            float bias = b1[feat];
#pragma unroll
            for (int r = 0; r < 4; ++r) {
                int node = rb + r;
                if (node < M) V[(size_t)node * 128 + feat] = f2bf(acc[nf][r] + bias);
            }
        }
    }
}

// ---------- histogram with rank recording ----------
__global__ void k_hist(const int* __restrict__ ei, int* __restrict__ deg,
                       int* __restrict__ rank, int E) {
    int e = blockIdx.x * blockDim.x + threadIdx.x;
    if (e < E) rank[e] = atomicAdd(deg + ei[E + e], 1);
}

// ---------- scan stage 1 ----------
__global__ void k_scan1(int* __restrict__ a, int* __restrict__ bsum, int N) {
    __shared__ int s0[256], s1[256];
    int tid = threadIdx.x;
    int n = blockIdx.x * 256 + tid;
    int v = (n < N) ? a[n] : 0;
    s0[tid] = v;
    __syncthreads();
    int* cur = s0; int* nxt = s1;
#pragma unroll
    for (int off = 1; off < 256; off <<= 1) {
        int val = cur[tid];
        if (tid >= off) val += cur[tid - off];
        nxt[tid] = val;
        __syncthreads();
        int* t = cur; cur = nxt; nxt = t;
    }
    if (n < N) a[n] = cur[tid] - v;
    if (tid == 255) bsum[blockIdx.x] = cur[255];
}

// ---------- scan stage 2 ----------
__global__ void k_scan2(int* __restrict__ bsum, int nb) {
    __shared__ int s0[256], s1[256];
    int tid = threadIdx.x;
    int v = (tid < nb) ? bsum[tid] : 0;
    s0[tid] = v;
    __syncthreads();
    int* cur = s0; int* nxt = s1;
#pragma unroll
    for (int off = 1; off < 256; off <<= 1) {
        int val = cur[tid];
        if (tid >= off) val += cur[tid - off];
        nxt[tid] = val;
        __syncthreads();
        int* t = cur; cur = nxt; nxt = t;
    }
    if (tid < nb) bsum[tid] = cur[tid] - v;
}

// ---------- scan stage 3 ----------
__global__ void k_scan3(int* __restrict__ rowstart, const int* __restrict__ bsum,
                        int N, int E) {
    int n = blockIdx.x * 256 + threadIdx.x;
    if (n < N) rowstart[n] = rowstart[n] + bsum[n >> 8];
    if (n == 0) rowstart[N] = E;
}

// ---------- CSR scatter (no atomics: pos = rowstart[t] + rank[e]) ----------
__global__ void k_scatter(const int* __restrict__ ei, const int* __restrict__ rowstart,
                          const int* __restrict__ rank, int* __restrict__ esrc, int E) {
    int e = blockIdx.x * blockDim.x + threadIdx.x;
    if (e < E) {
        int s = ei[e];
        int t = ei[E + e];
        esrc[rowstart[t] + rank[e]] = s;
    }
}

// ---------- fused: per-target weights + aggregate + LayerNorm ----------
// One wave per node. 8 edges/wave, 8 lanes/edge, 16 feats/lane.
template <int USE_XB>
__global__ __launch_bounds__(256) void k_fused(const float* __restrict__ x,
                                               const unsigned char* __restrict__ U,
                                               const unsigned short* __restrict__ V,
                                               const unsigned short* __restrict__ XB,
                                               const int* __restrict__ rowstart,
                                               const int* __restrict__ esrc,
                                               const float* __restrict__ W2,
                                               const float* __restrict__ b2,
                                               const float* __restrict__ gamma,
                                               const float* __restrict__ beta,
                                               float* __restrict__ out, int N) {
    int row = blockIdx.x * 4 + (threadIdx.x >> 6);
    if (row >= N) return;
    int lane = threadIdx.x & 63;
    int el = lane & 7;        // edge slot
    int q  = lane >> 3;       // feature group: feats [16q, 16q+16)

    float w2r[16];
#pragma unroll
    for (int i = 0; i < 16; ++i) w2r[i] = W2[16 * q + i];
    float b2s = b2[0];

    // v_t (+b1 folded), 16 feats, sequential bf16 load
    const unsigned short* vp = V + (size_t)row * 128 + 16 * q;
    uint4 va = *(const uint4*)vp;
    uint4 vb = *(const uint4*)(vp + 8);
    float vf[16];
    vf[0]  = bflo(va.x); vf[1]  = bfhi(va.x);
    vf[2]  = bflo(va.y); vf[3]  = bfhi(va.y);
    vf[4]  = bflo(va.z); vf[5]  = bfhi(va.z);
    vf[6]  = bflo(va.w); vf[7]  = bfhi(va.w);
    vf[8]  = bflo(vb.x); vf[9]  = bfhi(vb.x);
    vf[10] = bflo(vb.y); vf[11] = bfhi(vb.y);
    vf[12] = bflo(vb.z); vf[13] = bfhi(vb.z);
    vf[14] = bflo(vb.w); vf[15] = bfhi(vb.w);

    int st = rowstart[row];
    int en = rowstart[row + 1];

    // residual: x[t] in f32 (sequential)
    float2 xx = *(const float2*)(x + (size_t)row * 128 + 2 * lane);
    float a0 = xx.x, a1 = xx.y;

    for (int g = st; g < en; g += 8) {
        int e = g + el;
        bool val = (e < en);
        int s = val ? esrc[e] : 0;

        // u[s]: 16 fp8 feats = one uint4
        uint4 ua = *(const uint4*)(U + (size_t)s * 128 + 16 * q);
        f32x2 d0 = __builtin_amdgcn_cvt_pk_f32_fp8(ua.x, false);
        f32x2 d1 = __builtin_amdgcn_cvt_pk_f32_fp8(ua.x, true);
        f32x2 d2 = __builtin_amdgcn_cvt_pk_f32_fp8(ua.y, false);
        f32x2 d3 = __builtin_amdgcn_cvt_pk_f32_fp8(ua.y, true);
        f32x2 d4 = __builtin_amdgcn_cvt_pk_f32_fp8(ua.z, false);
        f32x2 d5 = __builtin_amdgcn_cvt_pk_f32_fp8(ua.z, true);
        f32x2 d6 = __builtin_amdgcn_cvt_pk_f32_fp8(ua.w, false);
        f32x2 d7 = __builtin_amdgcn_cvt_pk_f32_fp8(ua.w, true);

        float p = 0.0f;
        p = fmaf(fmaxf(d0.x + vf[0],  0.f), w2r[0],  p);
        p = fmaf(fmaxf(d0.y + vf[1],  0.f), w2r[1],  p);
        p = fmaf(fmaxf(d1.x + vf[2],  0.f), w2r[2],  p);
        p = fmaf(fmaxf(d1.y + vf[3],  0.f), w2r[3],  p);
        p = fmaf(fmaxf(d2.x + vf[4],  0.f), w2r[4],  p);
        p = fmaf(fmaxf(d2.y + vf[5],  0.f), w2r[5],  p);
        p = fmaf(fmaxf(d3.x + vf[6],  0.f), w2r[6],  p);
        p = fmaf(fmaxf(d3.y + vf[7],  0.f), w2r[7],  p);
        p = fmaf(fmaxf(d4.x + vf[8],  0.f), w2r[8],  p);
        p = fmaf(fmaxf(d4.y + vf[9],  0.f), w2r[9],  p);
        p = fmaf(fmaxf(d5.x + vf[10], 0.f), w2r[10], p);
        p = fmaf(fmaxf(d5.y + vf[11], 0.f), w2r[11], p);
        p = fmaf(fmaxf(d6.x + vf[12], 0.f), w2r[12], p);
        p = fmaf(fmaxf(d6.y + vf[13], 0.f), w2r[13], p);
        p = fmaf(fmaxf(d7.x + vf[14], 0.f), w2r[14], p);
        p = fmaf(fmaxf(d7.y + vf[15], 0.f), w2r[15], p);

        p += __shfl_xor(p, 8);
        p += __shfl_xor(p, 16);
        p += __shfl_xor(p, 32);

        float w = val ? 1.0f / (1.0f + __expf(-(p + b2s))) : 0.0f;

#pragma unroll
        for (int j = 0; j < 8; ++j) {
            float wj = __shfl(w, j);
            int   sj = __shfl(s, j);
            if (USE_XB) {
                unsigned int xv = *(const unsigned int*)(XB + (size_t)sj * 128 + 2 * lane);
                a0 = fmaf(wj, bflo(xv), a0);
                a1 = fmaf(wj, bfhi(xv), a1);
            } else {
                float2 xf = *(const float2*)(x + (size_t)sj * 128 + 2 * lane);
                a0 = fmaf(wj, xf.x, a0);
                a1 = fmaf(wj, xf.y, a1);
            }
        }
    }

    // LayerNorm
    float s = a0 + a1;
#pragma unroll
    for (int off = 32; off; off >>= 1) s += __shfl_xor(s, off);
    float mu = s * (1.0f / 128.0f);
    float d0v = a0 - mu, d1v = a1 - mu;
    float qq = d0v * d0v + d1v * d1v;
#pragma unroll
    for (int off = 32; off; off >>= 1) qq += __shfl_xor(qq, off);
    float rstd = rsqrtf(qq * (1.0f / 128.0f) + 1e-5f);
    float2 gg = *(const float2*)(gamma + 2 * lane);
    float2 bb = *(const float2*)(beta + 2 * lane);
    float2 o;
    o.x = d0v * rstd * gg.x + bb.x;
    o.y = d1v * rstd * gg.y + bb.y;
    *(float2*)(out + (size_t)row * 128 + 2 * lane) = o;
}

extern "C" void kernel_launch(void* const* d_in, const int* in_sizes, int n_in,
                              void* d_out, int out_size, void* d_ws, size_t ws_size,
                              hipStream_t stream) {
    const float* x     = (const float*)d_in[0];
    const int*   ei    = (const int*)d_in[1];
    const float* W1    = (const float*)d_in[2];
    const float* b1    = (const float*)d_in[3];
    const float* W2    = (const float*)d_in[4];
    const float* b2    = (const float*)d_in[5];
    const float* gamma = (const float*)d_in[6];
    const float* beta  = (const float*)d_in[7];
    float* out = (float*)d_out;

    const int N = in_sizes[0] / 128;   // 50000
    const int E = in_sizes[1] / 2;     // 800000
    const int NB = (N + 255) / 256;    // 196 scan blocks (<=256 required)

    // ---- workspace layout ----
    char* w = (char*)d_ws;
    size_t off = 0;
    auto alloc = [&](size_t bytes) {
        char* p = w + off;
        off = (off + bytes + 255) & ~(size_t)255;
        return p;
    };
    unsigned short* Bt       = (unsigned short*)alloc(256 * 128 * 2);       // 64 KB
    unsigned char*  U        = (unsigned char*)alloc((size_t)N * 128);      // 6.4 MB
    unsigned short* V        = (unsigned short*)alloc((size_t)N * 128 * 2); // 12.8 MB
    int*            rowstart = (int*)alloc((size_t)(N + 1) * 4);
    int*            bsum     = (int*)alloc(256 * 4);
    int*            rank     = (int*)alloc((size_t)E * 4);                  // 3.2 MB
    int*            esrc     = (int*)alloc((size_t)E * 4);                  // 3.2 MB
    size_t off_noxb = off;
    unsigned short* XB       = (unsigned short*)alloc((size_t)N * 128 * 2); // 12.8 MB
    bool use_xb = (off <= ws_size);
    if (!use_xb) { XB = nullptr; off = off_noxb; }

    int PB = (N + 256) / 256;          // covers rowstart zeroing
    if (PB < 128) PB = 128;            // covers Bt pack
    k_pack<<<PB, 256, 0, stream>>>(W1, Bt, rowstart, N);

    dim3 ggrid((N + 63) / 64, 4);
    k_gemm<<<ggrid, 256, 0, stream>>>(x, Bt, b1, U, V, XB, N);

    k_hist<<<(E + 255) / 256, 256, 0, stream>>>(ei, rowstart, rank, E);

    k_scan1<<<NB, 256, 0, stream>>>(rowstart, bsum, N);
    k_scan2<<<1, 256, 0, stream>>>(bsum, NB);
    k_scan3<<<NB, 256, 0, stream>>>(rowstart, bsum, N, E);

    k_scatter<<<(E + 255) / 256, 256, 0, stream>>>(ei, rowstart, rank, esrc, E);

    if (use_xb)
        k_fused<1><<<(N + 3) / 4, 256, 0, stream>>>(x, U, V, XB, rowstart, esrc,
                                                    W2, b2, gamma, beta, out, N);
    else
        k_fused<0><<<(N + 3) / 4, 256, 0, stream>>>(x, U, V, XB, rowstart, esrc,
                                                    W2, b2, gamma, beta, out, N);
}